// Round 5
// baseline (27317.130 us; speedup 1.0000x reference)
//
#include <hip/hip_runtime.h>
#include <math.h>

// Problem constants (match reference)
#define BB   16384
#define NOBS 512
#define NACT 64
#define DIN  1090      // 512+64+512+1+1
#define K0P  1120      // DIN padded to multiple of 32 (zeros)
#define HH   4096
#define DD   1024
#define KC   512

#define MC   2048      // batch chunk rows for the MLP
#define NCH  (BB / MC) // 8 chunks

#define F_DECAY 0.99f
#define F_OMD   0.01f
#define F_CC    0.25f
#define F_EPS   1e-5f

// fp32 emulation via fp16x2 split, 3 MFMA products (hh, hm, mh; mm dropped).
// W is scaled by WSCALE (exact pow2) so fp16 high parts are O(1);
// residuals are scaled by RSCALE (exact pow2) to stay in fp16 NORMAL range
// and accumulated in a second accumulator: x*w = (acc0 + acc1/RSCALE)/WSCALE.
// Numerics identical to rounds 1-3 (proven absmax 9.77e-4, same as baseline).
#define WSCALE   64.0f
#define WINV     0.015625f       // 1/64
#define RSCALE   2048.0f
#define RINV     4.8828125e-4f   // 1/2048

using half8 = __attribute__((ext_vector_type(8))) _Float16;  // MFMA A/B frag (4 VGPRs)
using f4v   = __attribute__((ext_vector_type(4))) float;     // MFMA C/D frag

#define AS1 __attribute__((address_space(1)))
#define AS3 __attribute__((address_space(3)))

static __device__ inline void split2(float x, _Float16& h, _Float16& m) {
  h = (_Float16)x;                              // RNE
  m = (_Float16)((x - (float)h) * RSCALE);      // x-h exact in fp32; *2048 exact
}

// tiled activation layout: [mtile][kstep][comp(2)][kg(4)][row(128)][j(8)] f16
// (8192 f16 = 16 KB contiguous per (mtile,kstep) -> global_load_lds, width 16)
// PROVEN correct end-to-end in round 1 (passed harness).
static __device__ inline size_t tiled_off(int m, int k, int ksteps) {
  return ((size_t)(m >> 7) * (size_t)ksteps + (size_t)(k >> 5)) * 8192
       + (size_t)((k >> 3) & 3) * 1024 + (size_t)(m & 127) * 8 + (size_t)(k & 7);
}

// ------------------------------------------------------------------
// Build one chunk of X0 = hstack(obs, action, next_obs, reward, term),
// padded, split to f16 (h, m*RSCALE) pairs in tiled layout.
// ------------------------------------------------------------------
__global__ __launch_bounds__(256) void build_x0_kernel(
    const float* __restrict__ obs, const float* __restrict__ act,
    const float* __restrict__ nobs, const float* __restrict__ rew,
    const float* __restrict__ term, _Float16* __restrict__ X0)
{
  const int i = blockIdx.x;
  const int t = threadIdx.x;
  for (int c = t; c < K0P; c += 256) {
    float v;
    if (c < NOBS)                 v = obs[(size_t)i * NOBS + c];
    else if (c < NOBS + NACT)     v = act[(size_t)i * NACT + (c - NOBS)];
    else if (c < 2*NOBS + NACT)   v = nobs[(size_t)i * NOBS + (c - NOBS - NACT)];
    else if (c == 1088)           v = rew[i];
    else if (c == 1089)           v = term[i];
    else                          v = 0.0f;
    _Float16 h, m; split2(v, h, m);
    const size_t o = tiled_off(i, c, K0P >> 5);
    X0[o]        = h;
    X0[o + 4096] = m;
  }
}

__global__ void init_kernel(int* __restrict__ cnt, float* __restrict__ lsum)
{
  const int t = threadIdx.x;
  if (t < KC) cnt[t] = 0;
  if (t == 0) *lsum = 0.0f;
}

__global__ __launch_bounds__(256) void zero_kernel(float* __restrict__ p, int n)
{
  const int i = blockIdx.x * 256 + threadIdx.x;
  if (i < n) p[i] = 0.0f;
}

// ------------------------------------------------------------------
// Emulated-fp32 GEMM, EXPLICIT 2-phase double-buffered pipeline.
// A: tiled split-f16 pairs (producer-split ONCE; staged via
//    global_load_lds width-16, zero VALU / zero regs in steady state).
// W: fp32 [K,N], split in-kernel (8 split2/thread/iter).
// BM=128, BN=64, 256 threads = 4 waves (2m x 2n), wave tile 64x32,
// dual accumulators = 64 AGPR/wave (no register cliff; ~<=170 total,
// 3 blocks/CU with 48 KB LDS). ONE __syncthreads per K-step; tile t+1
// (A gld + B reg-loads) is issued BEFORE tile t's MFMA section, so its
// latency hides under the full iteration body.
// MODE 0: relu + write tiled split-f16 pairs. MODE 1: fp32 C.
// ------------------------------------------------------------------
template<int MODE>
__global__ __launch_bounds__(256, 3) void gemm_pair_kernel(
    const _Float16* __restrict__ A, const float* __restrict__ W,
    const float* __restrict__ bias, _Float16* __restrict__ Ch,
    float* __restrict__ Cf, int N, int K, int Kreal)
{
  __shared__ __align__(16) _Float16 Alds[2][2][4][128][8];  // 32 KB (dbuf)
  __shared__ __align__(16) _Float16 Blds[2][2][4][64][8];   // 16 KB (dbuf)

  const int tid  = threadIdx.x;
  const int n0   = blockIdx.x * 64;
  const int m0   = blockIdx.y * 128;
  const int lane = tid & 63;
  const int wv   = tid >> 6;             // wave 0..3 (2m x 2n)
  const int wmo  = (wv >> 1) * 64;
  const int wno  = (wv & 1) * 32;
  const int lm   = lane & 15;            // m (A) / n (B) / col (C)
  const int kg   = lane >> 4;            // k-octet 0..3

  // B staging: col sbn 0..63, k-octet = wv
  const int sbn = tid & 63;

  const int ksteps = K >> 5;
  const _Float16* Atile = A + (size_t)(m0 >> 7) * (size_t)ksteps * 8192;

  f4v acc0[4][2], acc1[4][2];
  #pragma unroll
  for (int a = 0; a < 4; ++a)
    #pragma unroll
    for (int b = 0; b < 2; ++b) { acc0[a][b] = (f4v)0.0f; acc1[a][b] = (f4v)0.0f; }

  // ---- prologue: stage tile 0 into buf 0 ----
  {
    const _Float16* gb = Atile;                 // ks = 0
    _Float16* lb = &Alds[0][0][0][0][0];
    #pragma unroll
    for (int q = 0; q < 4; ++q) {
      const int chunk = wv * 4 + q;             // wave-uniform
      __builtin_amdgcn_global_load_lds(
          (const AS1 void*)(gb + chunk * 512 + lane * 8),
          (AS3 void*)(lb + chunk * 512), 16, 0, 0);
    }
    float bw[8];
    #pragma unroll
    for (int i = 0; i < 8; ++i) {
      const int kk = wv * 8 + i;
      bw[i] = (kk < Kreal) ? W[(size_t)kk * N + n0 + sbn] * WSCALE : 0.0f;
    }
    half8 vh, vm;
    #pragma unroll
    for (int i = 0; i < 8; ++i) { _Float16 h, m; split2(bw[i], h, m); vh[i] = h; vm[i] = m; }
    *(half8*)&Blds[0][0][wv][sbn][0] = vh;
    *(half8*)&Blds[0][1][wv][sbn][0] = vm;
  }
  __syncthreads();   // drains gld (vmcnt) + B writes (lgkm)

  int buf = 0;
  for (int ks = 0; ks < ksteps; ++ks) {
    const int nxt = ks + 1;
    const bool more = (nxt < ksteps);

    // ---- issue tile nxt's loads FIRST (in flight across whole body) ----
    float bw[8];
    if (more) {
      const _Float16* gb = Atile + (size_t)nxt * 8192;
      _Float16* lb = &Alds[buf ^ 1][0][0][0][0];
      #pragma unroll
      for (int q = 0; q < 4; ++q) {
        const int chunk = wv * 4 + q;
        __builtin_amdgcn_global_load_lds(
            (const AS1 void*)(gb + chunk * 512 + lane * 8),
            (AS3 void*)(lb + chunk * 512), 16, 0, 0);
      }
      #pragma unroll
      for (int i = 0; i < 8; ++i) {
        const int kk = nxt * 32 + wv * 8 + i;
        bw[i] = (kk < Kreal) ? W[(size_t)kk * N + n0 + sbn] * WSCALE : 0.0f;
      }
    }

    // ---- compute tile ks from buf ----
    half8 bh[2], bm[2];
    #pragma unroll
    for (int nt = 0; nt < 2; ++nt) {
      bh[nt] = *(const half8*)&Blds[buf][0][kg][wno + nt * 16 + lm][0];
      bm[nt] = *(const half8*)&Blds[buf][1][kg][wno + nt * 16 + lm][0];
    }
    #pragma unroll
    for (int mt = 0; mt < 4; ++mt) {
      const half8 ah = *(const half8*)&Alds[buf][0][kg][wmo + mt * 16 + lm][0];
      const half8 am = *(const half8*)&Alds[buf][1][kg][wmo + mt * 16 + lm][0];
      #pragma unroll
      for (int nt = 0; nt < 2; ++nt) {
        acc0[mt][nt] = __builtin_amdgcn_mfma_f32_16x16x32_f16(ah, bh[nt], acc0[mt][nt], 0, 0, 0); // hi*hi
        acc1[mt][nt] = __builtin_amdgcn_mfma_f32_16x16x32_f16(ah, bm[nt], acc1[mt][nt], 0, 0, 0); // hi*res
        acc1[mt][nt] = __builtin_amdgcn_mfma_f32_16x16x32_f16(am, bh[nt], acc1[mt][nt], 0, 0, 0); // res*hi
      }
    }

    // ---- split B(nxt) and write into buf^1 ----
    if (more) {
      half8 vh, vm;
      #pragma unroll
      for (int i = 0; i < 8; ++i) { _Float16 h, m; split2(bw[i], h, m); vh[i] = h; vm[i] = m; }
      *(half8*)&Blds[buf ^ 1][0][wv][sbn][0] = vh;
      *(half8*)&Blds[buf ^ 1][1][wv][sbn][0] = vm;
    }

    __syncthreads();   // vmcnt(0)+lgkmcnt(0) drain: tile nxt fully staged
    buf ^= 1;
  }

  // ---- epilogue ----
  float bias_v[2];
  #pragma unroll
  for (int nt = 0; nt < 2; ++nt) bias_v[nt] = bias[n0 + wno + nt * 16 + lm];

  #pragma unroll
  for (int mt = 0; mt < 4; ++mt)
    #pragma unroll
    for (int nt = 0; nt < 2; ++nt) {
      const int n = n0 + wno + nt * 16 + lm;
      #pragma unroll
      for (int r = 0; r < 4; ++r) {
        const int m = m0 + wmo + mt * 16 + kg * 4 + r;
        float v = (acc0[mt][nt][r] + acc1[mt][nt][r] * RINV) * WINV + bias_v[nt];
        if (MODE == 0) {
          v = fmaxf(v, 0.0f);
          _Float16 h, mr; split2(v, h, mr);
          const size_t o = tiled_off(m, n, N >> 5);
          Ch[o]        = h;
          Ch[o + 4096] = mr;
        } else {
          Cf[(size_t)m * N + n] = v;
        }
      }
    }
}

// ------------------------------------------------------------------
// fp32 vector GEMM (scores GEMM only)
// ------------------------------------------------------------------
__global__ __launch_bounds__(256) void sgemm_kernel(
    const float* __restrict__ A, const float* __restrict__ W,
    const float* __restrict__ bias, float* __restrict__ C,
    int M, int N, int K, int Kreal, float alpha)
{
  __shared__ float As[16][128];
  __shared__ float Bs[16][128];

  const int tid = threadIdx.x;
  const int n0 = blockIdx.x * 128;
  const int m0 = blockIdx.y * 128;

  const int ar = tid & 63;
  const int ak = (tid >> 6) << 2;
  const int bk = tid >> 5;
  const int bc = (tid & 31) << 2;
  const int tx = tid & 15;
  const int ty = tid >> 4;

  float acc[2][2][4][4];
  #pragma unroll
  for (int a = 0; a < 2; ++a)
    #pragma unroll
    for (int b = 0; b < 2; ++b)
      #pragma unroll
      for (int c = 0; c < 4; ++c)
        #pragma unroll
        for (int d = 0; d < 4; ++d) acc[a][b][c][d] = 0.0f;

  const float4 zero4 = make_float4(0.f, 0.f, 0.f, 0.f);

  for (int k0 = 0; k0 < K; k0 += 16) {
    float4 a0 = *(const float4*)(A + (size_t)(m0 + ar) * K + k0 + ak);
    float4 a1 = *(const float4*)(A + (size_t)(m0 + ar + 64) * K + k0 + ak);
    const int kr0 = k0 + bk, kr1 = k0 + bk + 8;
    float4 b0 = (kr0 < Kreal) ? *(const float4*)(W + (size_t)kr0 * N + n0 + bc) : zero4;
    float4 b1 = (kr1 < Kreal) ? *(const float4*)(W + (size_t)kr1 * N + n0 + bc) : zero4;

    __syncthreads();
    As[ak + 0][ar] = a0.x; As[ak + 1][ar] = a0.y;
    As[ak + 2][ar] = a0.z; As[ak + 3][ar] = a0.w;
    As[ak + 0][ar + 64] = a1.x; As[ak + 1][ar + 64] = a1.y;
    As[ak + 2][ar + 64] = a1.z; As[ak + 3][ar + 64] = a1.w;
    *(float4*)&Bs[bk][bc]     = b0;
    *(float4*)&Bs[bk + 8][bc] = b1;
    __syncthreads();

    #pragma unroll
    for (int kk = 0; kk < 16; ++kk) {
      const float4 av0 = *(const float4*)&As[kk][ty * 4];
      const float4 av1 = *(const float4*)&As[kk][ty * 4 + 64];
      const float4 bv0 = *(const float4*)&Bs[kk][tx * 4];
      const float4 bv1 = *(const float4*)&Bs[kk][tx * 4 + 64];
      const float am[2][4] = {{av0.x, av0.y, av0.z, av0.w}, {av1.x, av1.y, av1.z, av1.w}};
      const float bn[2][4] = {{bv0.x, bv0.y, bv0.z, bv0.w}, {bv1.x, bv1.y, bv1.z, bv1.w}};
      #pragma unroll
      for (int mi = 0; mi < 2; ++mi)
        #pragma unroll
        for (int ni = 0; ni < 2; ++ni)
          #pragma unroll
          for (int mj = 0; mj < 4; ++mj)
            #pragma unroll
            for (int nj = 0; nj < 4; ++nj)
              acc[mi][ni][mj][nj] += am[mi][mj] * bn[ni][nj];
    }
  }

  const float4 bi0 = *(const float4*)(bias + n0 + tx * 4);
  const float4 bi1 = *(const float4*)(bias + n0 + tx * 4 + 64);
  const float bb[2][4] = {{bi0.x, bi0.y, bi0.z, bi0.w}, {bi1.x, bi1.y, bi1.z, bi1.w}};

  #pragma unroll
  for (int mi = 0; mi < 2; ++mi)
    #pragma unroll
    for (int mj = 0; mj < 4; ++mj) {
      const int m = m0 + mi * 64 + ty * 4 + mj;
      #pragma unroll
      for (int ni = 0; ni < 2; ++ni) {
        float4 o;
        o.x = alpha * acc[mi][ni][mj][0] + bb[ni][0];
        o.y = alpha * acc[mi][ni][mj][1] + bb[ni][1];
        o.z = alpha * acc[mi][ni][mj][2] + bb[ni][2];
        o.w = alpha * acc[mi][ni][mj][3] + bb[ni][3];
        *(float4*)(C + (size_t)m * N + n0 + ni * 64 + tx * 4) = o;
      }
    }
}

// ------------------------------------------------------------------
__global__ __launch_bounds__(512) void esq_kernel(const float* __restrict__ emb,
                                                  float* __restrict__ esq)
{
  const int k = threadIdx.x;
  float s = 0.0f;
  for (int d = 0; d < DD; ++d) { const float v = emb[(size_t)d * KC + k]; s += v * v; }
  esq[k] = s;
}

__global__ __launch_bounds__(256) void transpose_kernel(const float* __restrict__ emb,
                                                        float* __restrict__ embT)
{
  const int t = blockIdx.x * 256 + threadIdx.x;
  const int d = t & (DD - 1);
  const int k = t >> 10;
  embT[t] = emb[(size_t)d * KC + k];
}

// ------------------------------------------------------------------
__global__ __launch_bounds__(64) void argmin_kernel(const float* __restrict__ S,
                                                    int* __restrict__ idx,
                                                    int* __restrict__ cnt)
{
  const int i = blockIdx.x;
  const int lane = threadIdx.x;
  const float* row = S + (size_t)i * KC;
  float best = 3.4e38f;
  int   bi   = 0x7fffffff;
  for (int k = lane; k < KC; k += 64) {
    const float v = row[k];
    if (v < best) { best = v; bi = k; }
  }
  #pragma unroll
  for (int off = 32; off > 0; off >>= 1) {
    const float ov = __shfl_down(best, off);
    const int   oi = __shfl_down(bi, off);
    if (ov < best || (ov == best && oi < bi)) { best = ov; bi = oi; }
  }
  if (lane == 0) { idx[i] = bi; atomicAdd(cnt + bi, 1); }
}

// ------------------------------------------------------------------
__global__ __launch_bounds__(512) void prefix_kernel(const int* __restrict__ cnt,
                                                     int* __restrict__ offs,
                                                     int* __restrict__ cursor)
{
  __shared__ int s[512];
  const int t = threadIdx.x;
  s[t] = cnt[t]; __syncthreads();
  for (int d = 1; d < 512; d <<= 1) {
    const int v = (t >= d) ? s[t - d] : 0;
    __syncthreads();
    s[t] += v;
    __syncthreads();
  }
  const int excl = (t == 0) ? 0 : s[t - 1];
  offs[t] = excl;
  cursor[t] = excl;
}

__global__ __launch_bounds__(256) void scatter_kernel(const int* __restrict__ idx,
                                                      int* __restrict__ cursor,
                                                      int* __restrict__ rows)
{
  const int i = blockIdx.x * 256 + threadIdx.x;
  const int k = idx[i];
  const int slot = atomicAdd(cursor + k, 1);
  rows[slot] = i;
}

// ------------------------------------------------------------------
__global__ __launch_bounds__(512) void finalize_cs_kernel(const int* __restrict__ cnt,
    const float* __restrict__ ecs,
    float* __restrict__ out_perp, float* __restrict__ out_cs, float* __restrict__ ws_cs)
{
  const int t = threadIdx.x;
  __shared__ float red[512];
  const float c  = (float)cnt[t];
  const float cs = F_DECAY * ecs[t] + F_OMD * c;
  red[t] = cs; __syncthreads();
  for (int s = 256; s > 0; s >>= 1) { if (t < s) red[t] += red[t + s]; __syncthreads(); }
  const float n = red[0]; __syncthreads();
  const float css = (cs + F_EPS) / (n + (float)KC * F_EPS) * n;
  out_cs[t] = css;
  ws_cs[t]  = css;
  const float p = c * (1.0f / (float)BB);
  red[t] = p * logf(p + 1e-10f); __syncthreads();
  for (int s = 256; s > 0; s >>= 1) { if (t < s) red[t] += red[t + s]; __syncthreads(); }
  if (t == 0) *out_perp = expf(-red[0]);
}

__global__ void finalize_loss_kernel(const float* __restrict__ lsum,
                                     float* __restrict__ out_loss)
{
  *out_loss = F_CC * lsum[0] * (1.0f / ((float)BB * (float)DD));
}

// ------------------------------------------------------------------
__global__ __launch_bounds__(256) void dw3_partial_kernel(const int* __restrict__ rows,
    const int* __restrict__ offs, const int* __restrict__ cnt,
    const float* __restrict__ z, float* __restrict__ dwacc)
{
  const int k = blockIdx.x;
  const int s = blockIdx.y;
  const int c = cnt[k];
  const int begin = s * 256;
  if (begin >= c) return;
  const int nrows = min(c - begin, 256);
  const int o = offs[k] + begin;
  const int t = threadIdx.x;

  __shared__ int rlist[256];
  if (t < nrows) rlist[t] = rows[o + t];
  __syncthreads();

  float a0 = 0.f, a1 = 0.f, a2 = 0.f, a3 = 0.f;
  for (int r = 0; r < nrows; ++r) {
    const float* zr = z + (size_t)rlist[r] * DD;
    a0 += zr[t]; a1 += zr[t + 256]; a2 += zr[t + 512]; a3 += zr[t + 768];
  }
  atomicAdd(&dwacc[(size_t)(t      ) * KC + k], a0);
  atomicAdd(&dwacc[(size_t)(t + 256) * KC + k], a1);
  atomicAdd(&dwacc[(size_t)(t + 512) * KC + k], a2);
  atomicAdd(&dwacc[(size_t)(t + 768) * KC + k], a3);
}

__global__ __launch_bounds__(256) void dw3_final_kernel(const float* __restrict__ dwacc,
    const float* __restrict__ edw, const float* __restrict__ wcs,
    float* __restrict__ out_emb)
{
  const size_t t = (size_t)blockIdx.x * 256 + threadIdx.x;  // t = d*KC + k
  const int k = (int)(t & (KC - 1));
  out_emb[t] = (F_DECAY * edw[t] + F_OMD * dwacc[t]) / wcs[k];
}

// ------------------------------------------------------------------
__global__ __launch_bounds__(256) void gather_kernel(const int* __restrict__ idx,
    const float* __restrict__ embT, float* zq, float* __restrict__ lsum)
{
  const int i = blockIdx.x;
  const int t = threadIdx.x;
  const int id = idx[i];
  const float4 q  = *(const float4*)(embT + (size_t)id * DD + t * 4);
  const float4 zv = *(const float4*)(zq   + (size_t)i  * DD + t * 4);
  *(float4*)(zq + (size_t)i * DD + t * 4) = q;
  const float dx = q.x - zv.x, dy = q.y - zv.y, dz = q.z - zv.z, dw = q.w - zv.w;
  float s = dx * dx + dy * dy + dz * dz + dw * dw;

  __shared__ float red[256];
  red[t] = s; __syncthreads();
  for (int st = 128; st > 0; st >>= 1) { if (t < st) red[t] += red[t + st]; __syncthreads(); }
  if (t == 0) atomicAdd(lsum, red[0]);
}

// ------------------------------------------------------------------
extern "C" void kernel_launch(void* const* d_in, const int* in_sizes, int n_in,
                              void* d_out, int out_size, void* d_ws, size_t ws_size,
                              hipStream_t stream)
{
  const float* obs  = (const float*)d_in[0];
  const float* act  = (const float*)d_in[1];
  const float* nobs = (const float*)d_in[2];
  const float* rew  = (const float*)d_in[3];
  const float* term = (const float*)d_in[4];
  const float* w0 = (const float*)d_in[5];  const float* b0 = (const float*)d_in[6];
  const float* w1 = (const float*)d_in[7];  const float* b1 = (const float*)d_in[8];
  const float* w2 = (const float*)d_in[9];  const float* b2 = (const float*)d_in[10];
  const float* w3 = (const float*)d_in[11]; const float* b3 = (const float*)d_in[12];
  const float* wl = (const float*)d_in[13]; const float* bl = (const float*)d_in[14];
  const float* emb = (const float*)d_in[15];
  const float* ecs = (const float*)d_in[16];
  const float* edw = (const float*)d_in[17];

  // ---- workspace layout — byte-identical footprint to round 1 (proven fit)
  // bufX: MC*K0P*2 f16 (tiled split X0)   = 9,175,040 B
  // bufA: MC*HH*2  f16 (tiled split acts) = 33,554,432 B
  // bufB: MC*HH*2  f16                    = 33,554,432 B
  _Float16* bufX = (_Float16*)d_ws;
  _Float16* bufA = bufX + (size_t)MC * K0P * 2;
  _Float16* bufB = bufA + (size_t)MC * HH * 2;
  // post-MLP overlays (used only after all GEMMs):
  float* S    = (float*)bufA;                     // BB*KC = 8,388,608 floats (exact fit)
  float* esq  = (float*)bufB;                     // KC
  float* embT = esq + KC;                         // KC*DD
  int*   idx  = (int*)(embT + (size_t)KC * DD);   // BB
  int*   cnt  = idx + BB;                         // KC
  float* lsum = (float*)(cnt + KC);               // 1
  float* wcs  = lsum + 1;                         // KC
  int*   offs = (int*)(wcs + KC);                 // KC
  int*   curs = offs + KC;                        // KC
  int*   rows = curs + KC;                        // BB
  float* dwacc= (float*)(rows + BB);              // DD*KC (tail ~4.3 MB, inside bufB)

  float* out      = (float*)d_out;
  float* zq       = out;                          // z here; gather overwrites with q_st
  float* out_loss = out + (size_t)BB * DD;
  float* out_perp = out_loss + 1;
  float* out_emb  = out_perp + 1;
  float* out_cs   = out_emb + (size_t)DD * KC;

  const dim3 blk(256);

  // ---- MLP in batch chunks (emulated-fp32 fp16x2 MFMA GEMMs) ----
  for (int c = 0; c < NCH; ++c) {
    const size_t c0 = (size_t)c * MC;
    build_x0_kernel<<<dim3(MC), blk, 0, stream>>>(obs + c0 * NOBS, act + c0 * NACT,
                                                  nobs + c0 * NOBS, rew + c0, term + c0, bufX);
    gemm_pair_kernel<0><<<dim3(HH/64, MC/128), blk, 0, stream>>>(bufX, w0, b0, bufA, nullptr, HH, K0P, DIN);
    gemm_pair_kernel<0><<<dim3(HH/64, MC/128), blk, 0, stream>>>(bufA, w1, b1, bufB, nullptr, HH, HH,  HH);
    gemm_pair_kernel<0><<<dim3(HH/64, MC/128), blk, 0, stream>>>(bufB, w2, b2, bufA, nullptr, HH, HH,  HH);
    gemm_pair_kernel<0><<<dim3(HH/64, MC/128), blk, 0, stream>>>(bufA, w3, b3, bufB, nullptr, HH, HH,  HH);
    gemm_pair_kernel<1><<<dim3(DD/64, MC/128), blk, 0, stream>>>(bufB, wl, bl, nullptr, zq + c0 * DD, DD, HH, HH);
  }

  // ---- VQ phase (unchanged, fp32) ----
  init_kernel<<<1, 512, 0, stream>>>(cnt, lsum);
  zero_kernel<<<dim3((DD * KC) / 256), blk, 0, stream>>>(dwacc, DD * KC);
  esq_kernel<<<1, 512, 0, stream>>>(emb, esq);
  sgemm_kernel<<<dim3(KC/128, BB/128), blk, 0, stream>>>(zq, emb, esq, S, BB, KC, DD, DD, -2.0f);
  argmin_kernel<<<dim3(BB), dim3(64), 0, stream>>>(S, idx, cnt);
  prefix_kernel<<<1, 512, 0, stream>>>(cnt, offs, curs);
  scatter_kernel<<<dim3(BB/256), blk, 0, stream>>>(idx, curs, rows);
  finalize_cs_kernel<<<1, 512, 0, stream>>>(cnt, ecs, out_perp, out_cs, wcs);
  dw3_partial_kernel<<<dim3(KC, BB/256), blk, 0, stream>>>(rows, offs, cnt, zq, dwacc);
  dw3_final_kernel<<<dim3((DD*KC)/256), blk, 0, stream>>>(dwacc, edw, wcs, out_emb);
  transpose_kernel<<<dim3((KC*DD)/256), blk, 0, stream>>>(emb, embT);
  gather_kernel<<<dim3(BB), blk, 0, stream>>>(idx, embT, zq, lsum);
  finalize_loss_kernel<<<1, 1, 0, stream>>>(lsum, out_loss);
}

// Round 7
// 9745.444 us; speedup vs baseline: 2.8031x; 2.8031x over previous
//
#include <hip/hip_runtime.h>
#include <math.h>

// Problem constants (match reference)
#define BB   16384
#define NOBS 512
#define NACT 64
#define DIN  1090      // 512+64+512+1+1
#define K0P  1120      // DIN padded to multiple of 32 (zeros)
#define HH   4096
#define DD   1024
#define KC   512

#define MC   2048      // batch chunk rows for the MLP
#define NCH  (BB / MC) // 8 chunks

#define F_DECAY 0.99f
#define F_OMD   0.01f
#define F_CC    0.25f
#define F_EPS   1e-5f

// fp32 emulation via fp16x2 split, 3 MFMA products (hh, hm, mh; mm dropped).
// W is scaled by WSCALE (exact pow2) so fp16 high parts are O(1);
// residuals are scaled by RSCALE (exact pow2) to stay in fp16 NORMAL range
// and accumulated in a second accumulator: x*w = (acc0 + acc1/RSCALE)/WSCALE.
// Numerics proven in rounds 1-3/5 (absmax 9.77e-4, same as baseline).
#define WSCALE   64.0f
#define WINV     0.015625f       // 1/64
#define RSCALE   2048.0f
#define RINV     4.8828125e-4f   // 1/2048

using half8 = __attribute__((ext_vector_type(8))) _Float16;  // MFMA A/B frag (4 VGPRs)
using f4v   = __attribute__((ext_vector_type(4))) float;     // MFMA C/D frag

#define AS1 __attribute__((address_space(1)))
#define AS3 __attribute__((address_space(3)))

static __device__ inline void split2(float x, _Float16& h, _Float16& m) {
  h = (_Float16)x;                              // RNE
  m = (_Float16)((x - (float)h) * RSCALE);      // x-h exact in fp32; *2048 exact
}

// tiled activation layout: [mtile][kstep][comp(2)][kg(4)][row(128)][j(8)] f16
// (8192 f16 = 16 KB contiguous per (mtile,kstep) -> global_load_lds, width 16)
// PROVEN correct end-to-end in rounds 1 and 5 (passed harness).
static __device__ inline size_t tiled_off(int m, int k, int ksteps) {
  return ((size_t)(m >> 7) * (size_t)ksteps + (size_t)(k >> 5)) * 8192
       + (size_t)((k >> 3) & 3) * 1024 + (size_t)(m & 127) * 8 + (size_t)(k & 7);
}

// ------------------------------------------------------------------
// Build one chunk of X0 = hstack(obs, action, next_obs, reward, term),
// padded, split to f16 (h, m*RSCALE) pairs in tiled layout.
// ------------------------------------------------------------------
__global__ __launch_bounds__(256) void build_x0_kernel(
    const float* __restrict__ obs, const float* __restrict__ act,
    const float* __restrict__ nobs, const float* __restrict__ rew,
    const float* __restrict__ term, _Float16* __restrict__ X0)
{
  const int i = blockIdx.x;
  const int t = threadIdx.x;
  for (int c = t; c < K0P; c += 256) {
    float v;
    if (c < NOBS)                 v = obs[(size_t)i * NOBS + c];
    else if (c < NOBS + NACT)     v = act[(size_t)i * NACT + (c - NOBS)];
    else if (c < 2*NOBS + NACT)   v = nobs[(size_t)i * NOBS + (c - NOBS - NACT)];
    else if (c == 1088)           v = rew[i];
    else if (c == 1089)           v = term[i];
    else                          v = 0.0f;
    _Float16 h, m; split2(v, h, m);
    const size_t o = tiled_off(i, c, K0P >> 5);
    X0[o]        = h;
    X0[o + 4096] = m;
  }
}

__global__ void init_kernel(int* __restrict__ cnt, float* __restrict__ lsum)
{
  const int t = threadIdx.x;
  if (t < KC) cnt[t] = 0;
  if (t == 0) *lsum = 0.0f;
}

__global__ __launch_bounds__(256) void zero_kernel(float* __restrict__ p, int n)
{
  const int i = blockIdx.x * 256 + threadIdx.x;
  if (i < n) p[i] = 0.0f;
}

// ------------------------------------------------------------------
// Emulated-fp32 GEMM with COUNTED-vmcnt 3-deep pipeline (guide T3+T4).
// The round-5 failure mode: __syncthreads drains vmcnt(0), so any
// global_load_lds prefetch only stays in flight for ONE loop body.
// Here: raw s_barrier + "s_waitcnt vmcnt(12) lgkmcnt(0)" — tile t+2's
// 12 loads (4 A-gld_lds + 8 B-reg loads) REMAIN IN FLIGHT across the
// barrier; only tile t+1's loads must land. In-flight ~2 bodies.
//
// Invariant entering iteration t:
//   Alds[t%3]       = tile t, landed (drained by iter t-1's vmcnt(12))
//   Alds[(t+1)%3]   = tile t+1, in flight
//   Blds[t%2]       = B(t) split, in LDS
//   bw1[]           = B(t+1) raw regs, in flight
// Body: issue A(t+2)->Alds[(t+2)%3] and B(t+2)->bw2 (always issued,
// clamped addresses -> wave-uniform vmcnt counts); MFMA tile t;
// split bw1 -> Blds[(t+1)%2]; bw1=bw2; vmcnt(12)+lgkmcnt(0); s_barrier.
// WAR-safe: buffer written at iter t is (t+2)%3==(t-1)%3, whose reads
// finished before iter t-1's lgkmcnt(0)+barrier; gld issued after it.
//
// BM=128, BN=64, 256 thr = 4 waves (2m x 2n), wave tile 64x32, dual acc
// = 64 AGPR. LDS 64 KB -> 2 blocks/CU. MODE 0: relu + tiled f16-pair
// out. MODE 1: fp32 out.
// ------------------------------------------------------------------
template<int MODE>
__global__ __launch_bounds__(256, 2) void gemm_pipe_kernel(
    const _Float16* __restrict__ A, const float* __restrict__ W,
    const float* __restrict__ bias, _Float16* __restrict__ Ch,
    float* __restrict__ Cf, int N, int K, int Kreal)
{
  // per A-buffer layout: [comp(2)][kg(4)][row(128)][j(8)] = 8192 f16 = 16 KB
  __shared__ __align__(16) _Float16 Alds[3][8192];   // 48 KB
  // per B-buffer layout: [comp(2)][kg(4)][col(64)][j(8)] = 4096 f16 = 8 KB
  __shared__ __align__(16) _Float16 Blds[2][4096];   // 16 KB

  const int tid  = threadIdx.x;
  const int n0   = blockIdx.x * 64;
  const int m0   = blockIdx.y * 128;
  const int lane = tid & 63;
  const int wv   = tid >> 6;             // wave 0..3 (2m x 2n)
  const int wmo  = (wv >> 1) * 64;
  const int wno  = (wv & 1) * 32;
  const int lm   = lane & 15;            // m (A) / n (B) / col (C)
  const int kg   = lane >> 4;            // k-octet 0..3

  const int sbn = tid & 63;              // B staging col; k-octet = wv
  const float* Wc = W + n0 + sbn;

  const int nt = K >> 5;
  const _Float16* Atile = A + (size_t)(m0 >> 7) * (size_t)nt * 8192;

  f4v acc0[4][2], acc1[4][2];
  #pragma unroll
  for (int a = 0; a < 4; ++a)
    #pragma unroll
    for (int b = 0; b < 2; ++b) { acc0[a][b] = (f4v)0.0f; acc1[a][b] = (f4v)0.0f; }

  float bw1[8], bw2[8];

  // ---- prologue: A(0)->buf0, A(1)->buf1, B(0)->regs, B(1)->bw1 ----
  {
    #pragma unroll
    for (int b = 0; b < 2; ++b) {
      const _Float16* gb = Atile + (size_t)b * 8192;
      _Float16* lb = &Alds[b][0];
      #pragma unroll
      for (int q = 0; q < 4; ++q) {
        const int chunk = wv * 4 + q;             // wave-uniform
        __builtin_amdgcn_global_load_lds(
            (const AS1 void*)(gb + chunk * 512 + lane * 8),
            (AS3 void*)(lb + chunk * 512), 16, 0, 0);
      }
    }
    float bw0[8];
    #pragma unroll
    for (int i = 0; i < 8; ++i) {                 // B(0)
      const int kk = wv * 8 + i;
      const int kc = (kk < Kreal) ? kk : (Kreal - 1);
      const float raw = Wc[(size_t)kc * N];
      bw0[i] = (kk < Kreal) ? raw * WSCALE : 0.0f;
    }
    #pragma unroll
    for (int i = 0; i < 8; ++i) {                 // B(1)
      const int kk = 32 + wv * 8 + i;
      const int kc = (kk < Kreal) ? kk : (Kreal - 1);
      const float raw = Wc[(size_t)kc * N];
      bw1[i] = (kk < Kreal) ? raw * WSCALE : 0.0f;
    }
    // split B(0) -> Blds[0] (compiler waits bw0's loads here)
    half8 vh, vm;
    #pragma unroll
    for (int i = 0; i < 8; ++i) { _Float16 h, m; split2(bw0[i], h, m); vh[i] = h; vm[i] = m; }
    *(half8*)&Blds[0][       wv * 512 + sbn * 8] = vh;
    *(half8*)&Blds[0][2048 + wv * 512 + sbn * 8] = vm;
  }
  asm volatile("s_waitcnt vmcnt(12) lgkmcnt(0)" ::: "memory");
  __builtin_amdgcn_sched_barrier(0);
  __builtin_amdgcn_s_barrier();
  __builtin_amdgcn_sched_barrier(0);

  int aR = 0, bR = 0;
  for (int t = 0; t < nt; ++t) {
    const int pf = (t + 2 < nt) ? (t + 2) : (nt - 1);   // clamped prefetch idx
    int aW = aR + 2; if (aW >= 3) aW -= 3;
    const int bW = bR ^ 1;

    // ---- 1. A(t+2) -> Alds[aW] (stays in flight across the barrier) ----
    {
      const _Float16* gb = Atile + (size_t)pf * 8192;
      _Float16* lb = &Alds[aW][0];
      #pragma unroll
      for (int q = 0; q < 4; ++q) {
        const int chunk = wv * 4 + q;
        __builtin_amdgcn_global_load_lds(
            (const AS1 void*)(gb + chunk * 512 + lane * 8),
            (AS3 void*)(lb + chunk * 512), 16, 0, 0);
      }
    }
    // ---- 2. B(t+2) -> bw2 (always 8 loads, clamped: uniform vmcnt) ----
    #pragma unroll
    for (int i = 0; i < 8; ++i) {
      const int kk = pf * 32 + wv * 8 + i;
      const int kc = (kk < Kreal) ? kk : (Kreal - 1);
      const float raw = Wc[(size_t)kc * N];
      bw2[i] = (kk < Kreal) ? raw * WSCALE : 0.0f;
    }

    // ---- 3. MFMA on tile t from Alds[aR], Blds[bR] ----
    half8 bh[2], bm[2];
    #pragma unroll
    for (int nt2 = 0; nt2 < 2; ++nt2) {
      const int col = wno + nt2 * 16 + lm;
      bh[nt2] = *(const half8*)&Blds[bR][       kg * 512 + col * 8];
      bm[nt2] = *(const half8*)&Blds[bR][2048 + kg * 512 + col * 8];
    }
    #pragma unroll
    for (int mt = 0; mt < 4; ++mt) {
      const int row = wmo + mt * 16 + lm;
      const half8 ah = *(const half8*)&Alds[aR][       kg * 1024 + row * 8];
      const half8 am = *(const half8*)&Alds[aR][4096 + kg * 1024 + row * 8];
      #pragma unroll
      for (int nt2 = 0; nt2 < 2; ++nt2) {
        acc0[mt][nt2] = __builtin_amdgcn_mfma_f32_16x16x32_f16(ah, bh[nt2], acc0[mt][nt2], 0, 0, 0); // hi*hi
        acc1[mt][nt2] = __builtin_amdgcn_mfma_f32_16x16x32_f16(ah, bm[nt2], acc1[mt][nt2], 0, 0, 0); // hi*res
        acc1[mt][nt2] = __builtin_amdgcn_mfma_f32_16x16x32_f16(am, bh[nt2], acc1[mt][nt2], 0, 0, 0); // res*hi
      }
    }

    // ---- 4. split B(t+1) -> Blds[bW] (compiler waits bw1's loads) ----
    {
      half8 vh, vm;
      #pragma unroll
      for (int i = 0; i < 8; ++i) { _Float16 h, m; split2(bw1[i], h, m); vh[i] = h; vm[i] = m; }
      *(half8*)&Blds[bW][       wv * 512 + sbn * 8] = vh;
      *(half8*)&Blds[bW][2048 + wv * 512 + sbn * 8] = vm;
    }
    // ---- 5. rotate B regs ----
    #pragma unroll
    for (int i = 0; i < 8; ++i) bw1[i] = bw2[i];

    // ---- 6. counted drain + raw barrier (T4: NEVER vmcnt(0) here) ----
    asm volatile("s_waitcnt vmcnt(12) lgkmcnt(0)" ::: "memory");
    __builtin_amdgcn_sched_barrier(0);
    __builtin_amdgcn_s_barrier();
    __builtin_amdgcn_sched_barrier(0);

    aR += 1; if (aR == 3) aR = 0;
    bR = bW;
  }

  // ---- epilogue ----
  float bias_v[2];
  #pragma unroll
  for (int nt2 = 0; nt2 < 2; ++nt2) bias_v[nt2] = bias[n0 + wno + nt2 * 16 + lm];

  #pragma unroll
  for (int mt = 0; mt < 4; ++mt)
    #pragma unroll
    for (int nt2 = 0; nt2 < 2; ++nt2) {
      const int n = n0 + wno + nt2 * 16 + lm;
      #pragma unroll
      for (int r = 0; r < 4; ++r) {
        const int m = m0 + wmo + mt * 16 + kg * 4 + r;
        float v = (acc0[mt][nt2][r] + acc1[mt][nt2][r] * RINV) * WINV + bias_v[nt2];
        if (MODE == 0) {
          v = fmaxf(v, 0.0f);
          _Float16 h, mr; split2(v, h, mr);
          const size_t o = tiled_off(m, n, N >> 5);
          Ch[o]        = h;
          Ch[o + 4096] = mr;
        } else {
          Cf[(size_t)m * N + n] = v;
        }
      }
    }
}

// ------------------------------------------------------------------
// fp32 vector GEMM (scores GEMM only)
// ------------------------------------------------------------------
__global__ __launch_bounds__(256) void sgemm_kernel(
    const float* __restrict__ A, const float* __restrict__ W,
    const float* __restrict__ bias, float* __restrict__ C,
    int M, int N, int K, int Kreal, float alpha)
{
  __shared__ float As[16][128];
  __shared__ float Bs[16][128];

  const int tid = threadIdx.x;
  const int n0 = blockIdx.x * 128;
  const int m0 = blockIdx.y * 128;

  const int ar = tid & 63;
  const int ak = (tid >> 6) << 2;
  const int bk = tid >> 5;
  const int bc = (tid & 31) << 2;
  const int tx = tid & 15;
  const int ty = tid >> 4;

  float acc[2][2][4][4];
  #pragma unroll
  for (int a = 0; a < 2; ++a)
    #pragma unroll
    for (int b = 0; b < 2; ++b)
      #pragma unroll
      for (int c = 0; c < 4; ++c)
        #pragma unroll
        for (int d = 0; d < 4; ++d) acc[a][b][c][d] = 0.0f;

  const float4 zero4 = make_float4(0.f, 0.f, 0.f, 0.f);

  for (int k0 = 0; k0 < K; k0 += 16) {
    float4 a0 = *(const float4*)(A + (size_t)(m0 + ar) * K + k0 + ak);
    float4 a1 = *(const float4*)(A + (size_t)(m0 + ar + 64) * K + k0 + ak);
    const int kr0 = k0 + bk, kr1 = k0 + bk + 8;
    float4 b0 = (kr0 < Kreal) ? *(const float4*)(W + (size_t)kr0 * N + n0 + bc) : zero4;
    float4 b1 = (kr1 < Kreal) ? *(const float4*)(W + (size_t)kr1 * N + n0 + bc) : zero4;

    __syncthreads();
    As[ak + 0][ar] = a0.x; As[ak + 1][ar] = a0.y;
    As[ak + 2][ar] = a0.z; As[ak + 3][ar] = a0.w;
    As[ak + 0][ar + 64] = a1.x; As[ak + 1][ar + 64] = a1.y;
    As[ak + 2][ar + 64] = a1.z; As[ak + 3][ar + 64] = a1.w;
    *(float4*)&Bs[bk][bc]     = b0;
    *(float4*)&Bs[bk + 8][bc] = b1;
    __syncthreads();

    #pragma unroll
    for (int kk = 0; kk < 16; ++kk) {
      const float4 av0 = *(const float4*)&As[kk][ty * 4];
      const float4 av1 = *(const float4*)&As[kk][ty * 4 + 64];
      const float4 bv0 = *(const float4*)&Bs[kk][tx * 4];
      const float4 bv1 = *(const float4*)&Bs[kk][tx * 4 + 64];
      const float am[2][4] = {{av0.x, av0.y, av0.z, av0.w}, {av1.x, av1.y, av1.z, av1.w}};
      const float bn[2][4] = {{bv0.x, bv0.y, bv0.z, bv0.w}, {bv1.x, bv1.y, bv1.z, bv1.w}};
      #pragma unroll
      for (int mi = 0; mi < 2; ++mi)
        #pragma unroll
        for (int ni = 0; ni < 2; ++ni)
          #pragma unroll
          for (int mj = 0; mj < 4; ++mj)
            #pragma unroll
            for (int nj = 0; nj < 4; ++nj)
              acc[mi][ni][mj][nj] += am[mi][mj] * bn[ni][nj];
    }
  }

  const float4 bi0 = *(const float4*)(bias + n0 + tx * 4);
  const float4 bi1 = *(const float4*)(bias + n0 + tx * 4 + 64);
  const float bb[2][4] = {{bi0.x, bi0.y, bi0.z, bi0.w}, {bi1.x, bi1.y, bi1.z, bi1.w}};

  #pragma unroll
  for (int mi = 0; mi < 2; ++mi)
    #pragma unroll
    for (int mj = 0; mj < 4; ++mj) {
      const int m = m0 + mi * 64 + ty * 4 + mj;
      #pragma unroll
      for (int ni = 0; ni < 2; ++ni) {
        float4 o;
        o.x = alpha * acc[mi][ni][mj][0] + bb[ni][0];
        o.y = alpha * acc[mi][ni][mj][1] + bb[ni][1];
        o.z = alpha * acc[mi][ni][mj][2] + bb[ni][2];
        o.w = alpha * acc[mi][ni][mj][3] + bb[ni][3];
        *(float4*)(C + (size_t)m * N + n0 + ni * 64 + tx * 4) = o;
      }
    }
}

// ------------------------------------------------------------------
__global__ __launch_bounds__(512) void esq_kernel(const float* __restrict__ emb,
                                                  float* __restrict__ esq)
{
  const int k = threadIdx.x;
  float s = 0.0f;
  for (int d = 0; d < DD; ++d) { const float v = emb[(size_t)d * KC + k]; s += v * v; }
  esq[k] = s;
}

__global__ __launch_bounds__(256) void transpose_kernel(const float* __restrict__ emb,
                                                        float* __restrict__ embT)
{
  const int t = blockIdx.x * 256 + threadIdx.x;
  const int d = t & (DD - 1);
  const int k = t >> 10;
  embT[t] = emb[(size_t)d * KC + k];
}

// ------------------------------------------------------------------
__global__ __launch_bounds__(64) void argmin_kernel(const float* __restrict__ S,
                                                    int* __restrict__ idx,
                                                    int* __restrict__ cnt)
{
  const int i = blockIdx.x;
  const int lane = threadIdx.x;
  const float* row = S + (size_t)i * KC;
  float best = 3.4e38f;
  int   bi   = 0x7fffffff;
  for (int k = lane; k < KC; k += 64) {
    const float v = row[k];
    if (v < best) { best = v; bi = k; }
  }
  #pragma unroll
  for (int off = 32; off > 0; off >>= 1) {
    const float ov = __shfl_down(best, off);
    const int   oi = __shfl_down(bi, off);
    if (ov < best || (ov == best && oi < bi)) { best = ov; bi = oi; }
  }
  if (lane == 0) { idx[i] = bi; atomicAdd(cnt + bi, 1); }
}

// ------------------------------------------------------------------
__global__ __launch_bounds__(512) void prefix_kernel(const int* __restrict__ cnt,
                                                     int* __restrict__ offs,
                                                     int* __restrict__ cursor)
{
  __shared__ int s[512];
  const int t = threadIdx.x;
  s[t] = cnt[t]; __syncthreads();
  for (int d = 1; d < 512; d <<= 1) {
    const int v = (t >= d) ? s[t - d] : 0;
    __syncthreads();
    s[t] += v;
    __syncthreads();
  }
  const int excl = (t == 0) ? 0 : s[t - 1];
  offs[t] = excl;
  cursor[t] = excl;
}

__global__ __launch_bounds__(256) void scatter_kernel(const int* __restrict__ idx,
                                                      int* __restrict__ cursor,
                                                      int* __restrict__ rows)
{
  const int i = blockIdx.x * 256 + threadIdx.x;
  const int k = idx[i];
  const int slot = atomicAdd(cursor + k, 1);
  rows[slot] = i;
}

// ------------------------------------------------------------------
__global__ __launch_bounds__(512) void finalize_cs_kernel(const int* __restrict__ cnt,
    const float* __restrict__ ecs,
    float* __restrict__ out_perp, float* __restrict__ out_cs, float* __restrict__ ws_cs)
{
  const int t = threadIdx.x;
  __shared__ float red[512];
  const float c  = (float)cnt[t];
  const float cs = F_DECAY * ecs[t] + F_OMD * c;
  red[t] = cs; __syncthreads();
  for (int s = 256; s > 0; s >>= 1) { if (t < s) red[t] += red[t + s]; __syncthreads(); }
  const float n = red[0]; __syncthreads();
  const float css = (cs + F_EPS) / (n + (float)KC * F_EPS) * n;
  out_cs[t] = css;
  ws_cs[t]  = css;
  const float p = c * (1.0f / (float)BB);
  red[t] = p * logf(p + 1e-10f); __syncthreads();
  for (int s = 256; s > 0; s >>= 1) { if (t < s) red[t] += red[t + s]; __syncthreads(); }
  if (t == 0) *out_perp = expf(-red[0]);
}

__global__ void finalize_loss_kernel(const float* __restrict__ lsum,
                                     float* __restrict__ out_loss)
{
  *out_loss = F_CC * lsum[0] * (1.0f / ((float)BB * (float)DD));
}

// ------------------------------------------------------------------
__global__ __launch_bounds__(256) void dw3_partial_kernel(const int* __restrict__ rows,
    const int* __restrict__ offs, const int* __restrict__ cnt,
    const float* __restrict__ z, float* __restrict__ dwacc)
{
  const int k = blockIdx.x;
  const int s = blockIdx.y;
  const int c = cnt[k];
  const int begin = s * 256;
  if (begin >= c) return;
  const int nrows = min(c - begin, 256);
  const int o = offs[k] + begin;
  const int t = threadIdx.x;

  __shared__ int rlist[256];
  if (t < nrows) rlist[t] = rows[o + t];
  __syncthreads();

  float a0 = 0.f, a1 = 0.f, a2 = 0.f, a3 = 0.f;
  for (int r = 0; r < nrows; ++r) {
    const float* zr = z + (size_t)rlist[r] * DD;
    a0 += zr[t]; a1 += zr[t + 256]; a2 += zr[t + 512]; a3 += zr[t + 768];
  }
  atomicAdd(&dwacc[(size_t)(t      ) * KC + k], a0);
  atomicAdd(&dwacc[(size_t)(t + 256) * KC + k], a1);
  atomicAdd(&dwacc[(size_t)(t + 512) * KC + k], a2);
  atomicAdd(&dwacc[(size_t)(t + 768) * KC + k], a3);
}

__global__ __launch_bounds__(256) void dw3_final_kernel(const float* __restrict__ dwacc,
    const float* __restrict__ edw, const float* __restrict__ wcs,
    float* __restrict__ out_emb)
{
  const size_t t = (size_t)blockIdx.x * 256 + threadIdx.x;  // t = d*KC + k
  const int k = (int)(t & (KC - 1));
  out_emb[t] = (F_DECAY * edw[t] + F_OMD * dwacc[t]) / wcs[k];
}

// ------------------------------------------------------------------
__global__ __launch_bounds__(256) void gather_kernel(const int* __restrict__ idx,
    const float* __restrict__ embT, float* zq, float* __restrict__ lsum)
{
  const int i = blockIdx.x;
  const int t = threadIdx.x;
  const int id = idx[i];
  const float4 q  = *(const float4*)(embT + (size_t)id * DD + t * 4);
  const float4 zv = *(const float4*)(zq   + (size_t)i  * DD + t * 4);
  *(float4*)(zq + (size_t)i * DD + t * 4) = q;
  const float dx = q.x - zv.x, dy = q.y - zv.y, dz = q.z - zv.z, dw = q.w - zv.w;
  float s = dx * dx + dy * dy + dz * dz + dw * dw;

  __shared__ float red[256];
  red[t] = s; __syncthreads();
  for (int st = 128; st > 0; st >>= 1) { if (t < st) red[t] += red[t + st]; __syncthreads(); }
  if (t == 0) atomicAdd(lsum, red[0]);
}

// ------------------------------------------------------------------
extern "C" void kernel_launch(void* const* d_in, const int* in_sizes, int n_in,
                              void* d_out, int out_size, void* d_ws, size_t ws_size,
                              hipStream_t stream)
{
  const float* obs  = (const float*)d_in[0];
  const float* act  = (const float*)d_in[1];
  const float* nobs = (const float*)d_in[2];
  const float* rew  = (const float*)d_in[3];
  const float* term = (const float*)d_in[4];
  const float* w0 = (const float*)d_in[5];  const float* b0 = (const float*)d_in[6];
  const float* w1 = (const float*)d_in[7];  const float* b1 = (const float*)d_in[8];
  const float* w2 = (const float*)d_in[9];  const float* b2 = (const float*)d_in[10];
  const float* w3 = (const float*)d_in[11]; const float* b3 = (const float*)d_in[12];
  const float* wl = (const float*)d_in[13]; const float* bl = (const float*)d_in[14];
  const float* emb = (const float*)d_in[15];
  const float* ecs = (const float*)d_in[16];
  const float* edw = (const float*)d_in[17];

  // ---- workspace layout — byte-identical footprint to rounds 1/5 (proven fit)
  _Float16* bufX = (_Float16*)d_ws;
  _Float16* bufA = bufX + (size_t)MC * K0P * 2;
  _Float16* bufB = bufA + (size_t)MC * HH * 2;
  // post-MLP overlays (used only after all GEMMs):
  float* S    = (float*)bufA;                     // BB*KC = 8,388,608 floats (exact fit)
  float* esq  = (float*)bufB;                     // KC
  float* embT = esq + KC;                         // KC*DD
  int*   idx  = (int*)(embT + (size_t)KC * DD);   // BB
  int*   cnt  = idx + BB;                         // KC
  float* lsum = (float*)(cnt + KC);               // 1
  float* wcs  = lsum + 1;                         // KC
  int*   offs = (int*)(wcs + KC);                 // KC
  int*   curs = offs + KC;                        // KC
  int*   rows = curs + KC;                        // BB
  float* dwacc= (float*)(rows + BB);              // DD*KC (tail ~4.3 MB, inside bufB)

  float* out      = (float*)d_out;
  float* zq       = out;                          // z here; gather overwrites with q_st
  float* out_loss = out + (size_t)BB * DD;
  float* out_perp = out_loss + 1;
  float* out_emb  = out_perp + 1;
  float* out_cs   = out_emb + (size_t)DD * KC;

  const dim3 blk(256);

  // ---- MLP in batch chunks (emulated-fp32 fp16x2 MFMA GEMMs) ----
  for (int c = 0; c < NCH; ++c) {
    const size_t c0 = (size_t)c * MC;
    build_x0_kernel<<<dim3(MC), blk, 0, stream>>>(obs + c0 * NOBS, act + c0 * NACT,
                                                  nobs + c0 * NOBS, rew + c0, term + c0, bufX);
    gemm_pipe_kernel<0><<<dim3(HH/64, MC/128), blk, 0, stream>>>(bufX, w0, b0, bufA, nullptr, HH, K0P, DIN);
    gemm_pipe_kernel<0><<<dim3(HH/64, MC/128), blk, 0, stream>>>(bufA, w1, b1, bufB, nullptr, HH, HH,  HH);
    gemm_pipe_kernel<0><<<dim3(HH/64, MC/128), blk, 0, stream>>>(bufB, w2, b2, bufA, nullptr, HH, HH,  HH);
    gemm_pipe_kernel<0><<<dim3(HH/64, MC/128), blk, 0, stream>>>(bufA, w3, b3, bufB, nullptr, HH, HH,  HH);
    gemm_pipe_kernel<1><<<dim3(DD/64, MC/128), blk, 0, stream>>>(bufB, wl, bl, nullptr, zq + c0 * DD, DD, HH, HH);
  }

  // ---- VQ phase (unchanged, fp32) ----
  init_kernel<<<1, 512, 0, stream>>>(cnt, lsum);
  zero_kernel<<<dim3((DD * KC) / 256), blk, 0, stream>>>(dwacc, DD * KC);
  esq_kernel<<<1, 512, 0, stream>>>(emb, esq);
  sgemm_kernel<<<dim3(KC/128, BB/128), blk, 0, stream>>>(zq, emb, esq, S, BB, KC, DD, DD, -2.0f);
  argmin_kernel<<<dim3(BB), dim3(64), 0, stream>>>(S, idx, cnt);
  prefix_kernel<<<1, 512, 0, stream>>>(cnt, offs, curs);
  scatter_kernel<<<dim3(BB/256), blk, 0, stream>>>(idx, curs, rows);
  finalize_cs_kernel<<<1, 512, 0, stream>>>(cnt, ecs, out_perp, out_cs, wcs);
  dw3_partial_kernel<<<dim3(KC, BB/256), blk, 0, stream>>>(rows, offs, cnt, zq, dwacc);
  dw3_final_kernel<<<dim3((DD*KC)/256), blk, 0, stream>>>(dwacc, edw, wcs, out_emb);
  transpose_kernel<<<dim3((KC*DD)/256), blk, 0, stream>>>(emb, embT);
  gather_kernel<<<dim3(BB), blk, 0, stream>>>(idx, embT, zq, lsum);
  finalize_loss_kernel<<<1, 1, 0, stream>>>(lsum, out_loss);
}